// Round 1
// baseline (194.528 us; speedup 1.0000x reference)
//
#include <hip/hip_runtime.h>

// ---------------- problem constants (fixed by reference) ----------------
#define T_DIM 110
#define B_DIM 256
#define D_DIM 512
#define H_DIM 512
#define K_CAT 1024              // concat K: [fr(512) | fi(512)]
#define M_DIM (T_DIM * B_DIM)   // 28160
#define EPSV 1e-9f

typedef float f32x4 __attribute__((ext_vector_type(4)));
typedef short bf16x8 __attribute__((ext_vector_type(8)));

static __device__ __forceinline__ unsigned short f2bf(float f) {
    unsigned u = __builtin_bit_cast(unsigned, f);
    u += 0x7fffu + ((u >> 16) & 1u);      // round-to-nearest-even
    return (unsigned short)(u >> 16);
}

// ---------------- kernel 1: weight prep  Wp=W1+W2 | Wm=W1-W2 (bf16), bias=2*b1 ----
__global__ __launch_bounds__(256) void prep_w_kernel(
    const float* __restrict__ W1, const float* __restrict__ b1,
    const float* __restrict__ W2,
    unsigned short* __restrict__ Bt,   // [H][K_CAT] bf16  (B^T layout: [N][K])
    float* __restrict__ bias2)         // [H]
{
    int i = blockIdx.x * 256 + threadIdx.x;
    if (i < H_DIM) bias2[i] = 2.0f * b1[i];
    if (i >= H_DIM * K_CAT) return;
    int h = i / K_CAT;
    int k = i % K_CAT;
    float w;
    if (k < D_DIM) w = W1[h * D_DIM + k] + W2[h * D_DIM + k];
    else           w = W1[h * D_DIM + k - D_DIM] - W2[h * D_DIM + k - D_DIM];
    Bt[i] = f2bf(w);
}

// ---------------- kernel 2: fused features + scan -> A[M][K_CAT] bf16 ----------
// thread = one (b,d) pair; serial loop over t keeps pA/pB in registers.
__global__ __launch_bounds__(256) void feat_scan_kernel(
    const float* __restrict__ a, const float* __restrict__ v,
    const float* __restrict__ l, const float* __restrict__ qmask,
    const float* __restrict__ mu_a, const float* __restrict__ mu_v,
    const float* __restrict__ mu_l,
    const float* __restrict__ shifta, const float* __restrict__ shiftv,
    const float* __restrict__ turna, const float* __restrict__ turnb,
    unsigned short* __restrict__ A)    // [M][K_CAT] bf16
{
    int tid = blockIdx.x * blockDim.x + threadIdx.x;   // 0 .. B*D-1
    int b = tid / D_DIM;
    int d = tid % D_DIM;
    float sa = shifta[d];
    float sv = shiftv[d];
    float pAr = 0.f, pAi = 0.f, pBr = 0.f, pBi = 0.f;

    for (int t = 0; t < T_DIM; ++t) {
        size_t idx = ((size_t)(t * B_DIM + b)) * D_DIM + d;
        float av = a[idx] + sa;
        float vv = v[idx] + sv;
        float lv = l[idx];
        float sA, cA, sV, cV, sL, cL;
        __sincosf(av, &sA, &cA);
        __sincosf(vv, &sV, &cV);
        __sincosf(lv, &sL, &cL);
        float ma = mu_a[t], mv = mu_v[t], ml = mu_l[t];
        float fr = ml * cL + ma * cA + mv * cV;
        float fi = ml * sL + ma * sA + mv * sV;

        float qa = qmask[(size_t)(t * B_DIM + b) * 2];   // one-hot; qb = 1-qa
        bool isA = qa > 0.5f;

        if (t == 0) {
            // pA0 = qa ? temp0 : (1+1i);  pB0 = qb ? temp0 : (1+1i)
            pAr = isA ? fr : 1.0f;  pAi = isA ? fi : 1.0f;
            pBr = isA ? 1.0f : fr;  pBi = isA ? 1.0f : fi;
        } else {
            float ph = isA ? turna[(size_t)t * D_DIM + d] : turnb[(size_t)t * D_DIM + d];
            float pr = isA ? pAr : pBr;
            float pi = isA ? pAi : pBi;
            float sp, cp;
            __sincosf(ph, &sp, &cp);
            float tr = pr * cp - pi * sp;
            float ti = pr * sp + pi * cp;
            if (!(tr == 0.0f && ti == 0.0f)) {
                float inv = 1.0f / (sqrtf(tr * tr + ti * ti) + EPSV);
                tr *= inv; ti *= inv;
            }
            fr += tr;
            fi += ti;
            if (isA) { pAr = fr; pAi = fi; } else { pBr = fr; pBi = fi; }
        }
        size_t row = (size_t)(t * B_DIM + b) * K_CAT;
        A[row + d]         = f2bf(fr);
        A[row + D_DIM + d] = f2bf(fi);
    }
}

// ---------------- kernel 3: bf16 MFMA GEMM  C = A @ Bt^T + bias ---------------
// A [M][K_CAT] bf16, Bt [N][K_CAT] bf16, C [M][N] f32.
// 128x128 tile, 4 waves (2x2), each wave 64x64 via 4x4 frags of 16x16x32.
#define BM 128
#define BN 128
#define BK 32
#define LDS_PAD 40   // ushorts per row (80 B): breaks pow2 bank stride

__global__ __launch_bounds__(256) void gemm_kernel(
    const unsigned short* __restrict__ A,
    const unsigned short* __restrict__ Bt,
    const float* __restrict__ bias2,
    float* __restrict__ C)
{
    __shared__ __align__(16) unsigned short As[BM * LDS_PAD];
    __shared__ __align__(16) unsigned short Bs[BN * LDS_PAD];

    int tid = threadIdx.x;
    int wave = tid >> 6;
    int lane = tid & 63;
    int wr = wave >> 1;          // 0..1 (M dir)
    int wc = wave & 1;           // 0..1 (N dir)
    int m0 = blockIdx.x * BM;
    int n0 = blockIdx.y * BN;
    int lrow = lane & 15;
    int lk8 = (lane >> 4) * 8;   // k-offset of this lane's 8 elements

    f32x4 acc[4][4] = {};

    for (int k0 = 0; k0 < K_CAT; k0 += BK) {
        // -------- stage A,B tiles: 128 rows x 32 cols bf16 = 512 chunks of 16B each
        #pragma unroll
        for (int j = 0; j < 2; ++j) {
            int ch = tid + 256 * j;
            int row = ch >> 2;
            int cc = ch & 3;
            const uint4* gA = reinterpret_cast<const uint4*>(
                A + (size_t)(m0 + row) * K_CAT + k0 + cc * 8);
            *reinterpret_cast<uint4*>(&As[row * LDS_PAD + cc * 8]) = *gA;
            const uint4* gB = reinterpret_cast<const uint4*>(
                Bt + (size_t)(n0 + row) * K_CAT + k0 + cc * 8);
            *reinterpret_cast<uint4*>(&Bs[row * LDS_PAD + cc * 8]) = *gB;
        }
        __syncthreads();

        bf16x8 af[4], bfv[4];
        #pragma unroll
        for (int m = 0; m < 4; ++m)
            af[m] = *reinterpret_cast<const bf16x8*>(
                &As[(wr * 64 + m * 16 + lrow) * LDS_PAD + lk8]);
        #pragma unroll
        for (int n = 0; n < 4; ++n)
            bfv[n] = *reinterpret_cast<const bf16x8*>(
                &Bs[(wc * 64 + n * 16 + lrow) * LDS_PAD + lk8]);

        #pragma unroll
        for (int m = 0; m < 4; ++m)
            #pragma unroll
            for (int n = 0; n < 4; ++n)
                acc[m][n] = __builtin_amdgcn_mfma_f32_16x16x32_bf16(
                    af[m], bfv[n], acc[m][n], 0, 0, 0);
        __syncthreads();
    }

    // -------- epilogue: C/D layout col=lane&15, row=(lane>>4)*4+r  (guide m89/m91)
    int rbase = m0 + wr * 64 + (lane >> 4) * 4;
    int cbase = n0 + wc * 64;
    #pragma unroll
    for (int n = 0; n < 4; ++n) {
        int col = cbase + n * 16 + lrow;
        float bv = bias2[col];
        #pragma unroll
        for (int m = 0; m < 4; ++m) {
            int row0 = rbase + m * 16;
            #pragma unroll
            for (int r = 0; r < 4; ++r) {
                C[(size_t)(row0 + r) * H_DIM + col] = acc[m][n][r] + bv;
            }
        }
    }
}

// ---------------- launcher ----------------
extern "C" void kernel_launch(void* const* d_in, const int* in_sizes, int n_in,
                              void* d_out, int out_size, void* d_ws, size_t ws_size,
                              hipStream_t stream) {
    const float* a      = (const float*)d_in[0];
    const float* v      = (const float*)d_in[1];
    const float* l      = (const float*)d_in[2];
    const float* qmask  = (const float*)d_in[3];
    // d_in[4] umask: unused by reference
    const float* mu_a   = (const float*)d_in[5];
    const float* mu_v   = (const float*)d_in[6];
    const float* mu_l   = (const float*)d_in[7];
    const float* shifta = (const float*)d_in[8];
    const float* shiftv = (const float*)d_in[9];
    const float* turna  = (const float*)d_in[10];
    const float* turnb  = (const float*)d_in[11];
    const float* W1     = (const float*)d_in[12];
    const float* b1     = (const float*)d_in[13];
    const float* W2     = (const float*)d_in[14];
    // d_in[15] b2: cancels in xr+xi
    float* out = (float*)d_out;

    char* ws = (char*)d_ws;
    unsigned short* Afeat = (unsigned short*)ws;                       // M*K_CAT bf16
    size_t offB  = (size_t)M_DIM * K_CAT * sizeof(unsigned short);     // 57,671,680
    unsigned short* Bt = (unsigned short*)(ws + offB);                 // H*K_CAT bf16
    size_t offBias = offB + (size_t)H_DIM * K_CAT * sizeof(unsigned short);
    float* bias2 = (float*)(ws + offBias);

    prep_w_kernel<<<(H_DIM * K_CAT + 255) / 256, 256, 0, stream>>>(W1, b1, W2, Bt, bias2);
    feat_scan_kernel<<<(B_DIM * D_DIM) / 256, 256, 0, stream>>>(
        a, v, l, qmask, mu_a, mu_v, mu_l, shifta, shiftv, turna, turnb, Afeat);
    dim3 grid(M_DIM / BM, H_DIM / BN);
    gemm_kernel<<<grid, 256, 0, stream>>>(Afeat, Bt, bias2, out);
}

// Round 2
// 134.015 us; speedup vs baseline: 1.4515x; 1.4515x over previous
//
#include <hip/hip_runtime.h>

// ---------------- problem constants (fixed by reference) ----------------
#define T_DIM 110
#define B_DIM 256
#define D_DIM 512
#define H_DIM 512
#define K_CAT 1024              // concat K: [fr(512) | fi(512)]
#define M_DIM (T_DIM * B_DIM)   // 28160
#define BD    (B_DIM * D_DIM)   // 131072
#define EPSV 1e-9f

typedef float f32x4 __attribute__((ext_vector_type(4)));
typedef short bf16x8 __attribute__((ext_vector_type(8)));

static __device__ __forceinline__ unsigned short f2bf(float f) {
    unsigned u = __builtin_bit_cast(unsigned, f);
    u += 0x7fffu + ((u >> 16) & 1u);      // round-to-nearest-even
    return (unsigned short)(u >> 16);
}

// ---------------- kernel 1: weight prep  Wp=W1+W2 | Wm=W1-W2 (bf16), bias=2*b1 ----
__global__ __launch_bounds__(256) void prep_w_kernel(
    const float* __restrict__ W1, const float* __restrict__ b1,
    const float* __restrict__ W2,
    unsigned short* __restrict__ Bt,   // [H][K_CAT] bf16  (B^T layout: [N][K])
    float* __restrict__ bias2)         // [H]
{
    int i = blockIdx.x * 256 + threadIdx.x;
    if (i < H_DIM) bias2[i] = 2.0f * b1[i];
    if (i >= H_DIM * K_CAT) return;
    int h = i / K_CAT;
    int k = i % K_CAT;
    float w;
    if (k < D_DIM) w = W1[h * D_DIM + k] + W2[h * D_DIM + k];
    else           w = W1[h * D_DIM + k - D_DIM] - W2[h * D_DIM + k - D_DIM];
    Bt[i] = f2bf(w);
}

// ---------------- kernel 2: fused features + scan -> A[M][K_CAT] bf16 ----------
// thread = one (b,d) pair; serial over t with a 3-deep explicit prefetch ring.
// Named registers only (runtime-indexed arrays would spill to scratch).
__global__ __launch_bounds__(256) void feat_scan_kernel(
    const float* __restrict__ a, const float* __restrict__ v,
    const float* __restrict__ l, const float* __restrict__ qmask,
    const float* __restrict__ mu_a, const float* __restrict__ mu_v,
    const float* __restrict__ mu_l,
    const float* __restrict__ shifta, const float* __restrict__ shiftv,
    const float* __restrict__ turna, const float* __restrict__ turnb,
    unsigned short* __restrict__ A)    // [M][K_CAT] bf16
{
    const int tid = blockIdx.x * blockDim.x + threadIdx.x;   // 0 .. BD-1
    const int b = tid >> 9;          // D_DIM = 512
    const int d = tid & 511;
    const float sa = shifta[d];
    const float sv = shiftv[d];

    // ---- prefetch ring, depth 3 (slots 0=t, 1=t+1, 2=t+2) ----
    float a0,v0,l0,ta0,tb0,q0,ma0,mv0,ml0;
    float a1,v1,l1,ta1,tb1,q1,ma1,mv1,ml1;
    float a2,v2,l2,ta2,tb2,q2,ma2,mv2,ml2;

#define LOAD_INTO(A_,V_,L_,TA_,TB_,Q_,MA_,MV_,ML_, T_)                        \
    {                                                                          \
        const int t_ = (T_);                                                   \
        A_  = a[(size_t)t_ * BD + tid];                                        \
        V_  = v[(size_t)t_ * BD + tid];                                        \
        L_  = l[(size_t)t_ * BD + tid];                                        \
        TA_ = turna[t_ * D_DIM + d];                                           \
        TB_ = turnb[t_ * D_DIM + d];                                           \
        Q_  = qmask[(size_t)(t_ * B_DIM + b) * 2];                             \
        MA_ = mu_a[t_]; MV_ = mu_v[t_]; ML_ = mu_l[t_];                        \
    }

    LOAD_INTO(a0,v0,l0,ta0,tb0,q0,ma0,mv0,ml0, 0)
    LOAD_INTO(a1,v1,l1,ta1,tb1,q1,ma1,mv1,ml1, 1)
    LOAD_INTO(a2,v2,l2,ta2,tb2,q2,ma2,mv2,ml2, 2)

    float pAr = 0.f, pAi = 0.f, pBr = 0.f, pBi = 0.f;

    #pragma unroll 3
    for (int t = 0; t < T_DIM; ++t) {
        // ---- issue loads for t+3 first: 3 iterations of latency budget ----
        float an,vn,ln,tan_,tbn,qn,man,mvn,mln;
        const int tp = (t + 3 < T_DIM) ? t + 3 : T_DIM - 1;
        LOAD_INTO(an,vn,ln,tan_,tbn,qn,man,mvn,mln, tp)

        // ---- consume slot 0 (data for step t, loaded 3 iterations ago) ----
        float sA, cA, sV, cV, sL, cL;
        __sincosf(a0 + sa, &sA, &cA);
        __sincosf(v0 + sv, &sV, &cV);
        __sincosf(l0,      &sL, &cL);
        float fr = ml0 * cL + ma0 * cA + mv0 * cV;
        float fi = ml0 * sL + ma0 * sA + mv0 * sV;

        const bool isA = q0 > 0.5f;
        if (t == 0) {
            pAr = isA ? fr : 1.0f;  pAi = isA ? fi : 1.0f;
            pBr = isA ? 1.0f : fr;  pBi = isA ? 1.0f : fi;
        } else {
            float ph = isA ? ta0 : tb0;
            float pr = isA ? pAr : pBr;
            float pi = isA ? pAi : pBi;
            float sp, cp;
            __sincosf(ph, &sp, &cp);
            float tr = pr * cp - pi * sp;
            float ti = pr * sp + pi * cp;
            if (!(tr == 0.0f && ti == 0.0f)) {
                float inv = 1.0f / (sqrtf(tr * tr + ti * ti) + EPSV);
                tr *= inv; ti *= inv;
            }
            fr += tr;
            fi += ti;
            if (isA) { pAr = fr; pAi = fi; } else { pBr = fr; pBi = fi; }
        }

        const size_t row = (size_t)(t * B_DIM + b) * K_CAT;
        A[row + d]         = f2bf(fr);
        A[row + D_DIM + d] = f2bf(fi);

        // ---- rotate ring (vanishes under unroll-3 register renaming) ----
        a0=a1; v0=v1; l0=l1; ta0=ta1; tb0=tb1; q0=q1; ma0=ma1; mv0=mv1; ml0=ml1;
        a1=a2; v1=v2; l1=l2; ta1=ta2; tb1=tb2; q1=q2; ma1=ma2; mv1=mv2; ml1=ml2;
        a2=an; v2=vn; l2=ln; ta2=tan_; tb2=tbn; q2=qn; ma2=man; mv2=mvn; ml2=mln;
    }
#undef LOAD_INTO
}

// ---------------- kernel 3: bf16 MFMA GEMM  C = A @ Bt^T + bias ---------------
// A [M][K_CAT] bf16, Bt [N][K_CAT] bf16, C [M][N] f32.
// 128x128 tile, 4 waves (2x2), each wave 64x64 via 4x4 frags of 16x16x32.
#define BM 128
#define BN 128
#define BK 32
#define LDS_PAD 40   // ushorts per row (80 B): breaks pow2 bank stride

__global__ __launch_bounds__(256) void gemm_kernel(
    const unsigned short* __restrict__ A,
    const unsigned short* __restrict__ Bt,
    const float* __restrict__ bias2,
    float* __restrict__ C)
{
    __shared__ __align__(16) unsigned short As[BM * LDS_PAD];
    __shared__ __align__(16) unsigned short Bs[BN * LDS_PAD];

    int tid = threadIdx.x;
    int wave = tid >> 6;
    int lane = tid & 63;
    int wr = wave >> 1;          // 0..1 (M dir)
    int wc = wave & 1;           // 0..1 (N dir)
    int m0 = blockIdx.x * BM;
    int n0 = blockIdx.y * BN;
    int lrow = lane & 15;
    int lk8 = (lane >> 4) * 8;   // k-offset of this lane's 8 elements

    f32x4 acc[4][4] = {};

    for (int k0 = 0; k0 < K_CAT; k0 += BK) {
        // -------- stage A,B tiles: 128 rows x 32 cols bf16 = 512 chunks of 16B each
        #pragma unroll
        for (int j = 0; j < 2; ++j) {
            int ch = tid + 256 * j;
            int row = ch >> 2;
            int cc = ch & 3;
            const uint4* gA = reinterpret_cast<const uint4*>(
                A + (size_t)(m0 + row) * K_CAT + k0 + cc * 8);
            *reinterpret_cast<uint4*>(&As[row * LDS_PAD + cc * 8]) = *gA;
            const uint4* gB = reinterpret_cast<const uint4*>(
                Bt + (size_t)(n0 + row) * K_CAT + k0 + cc * 8);
            *reinterpret_cast<uint4*>(&Bs[row * LDS_PAD + cc * 8]) = *gB;
        }
        __syncthreads();

        bf16x8 af[4], bfv[4];
        #pragma unroll
        for (int m = 0; m < 4; ++m)
            af[m] = *reinterpret_cast<const bf16x8*>(
                &As[(wr * 64 + m * 16 + lrow) * LDS_PAD + lk8]);
        #pragma unroll
        for (int n = 0; n < 4; ++n)
            bfv[n] = *reinterpret_cast<const bf16x8*>(
                &Bs[(wc * 64 + n * 16 + lrow) * LDS_PAD + lk8]);

        #pragma unroll
        for (int m = 0; m < 4; ++m)
            #pragma unroll
            for (int n = 0; n < 4; ++n)
                acc[m][n] = __builtin_amdgcn_mfma_f32_16x16x32_bf16(
                    af[m], bfv[n], acc[m][n], 0, 0, 0);
        __syncthreads();
    }

    // -------- epilogue: C/D layout col=lane&15, row=(lane>>4)*4+r  (guide m89/m91)
    int rbase = m0 + wr * 64 + (lane >> 4) * 4;
    int cbase = n0 + wc * 64;
    #pragma unroll
    for (int n = 0; n < 4; ++n) {
        int col = cbase + n * 16 + lrow;
        float bv = bias2[col];
        #pragma unroll
        for (int m = 0; m < 4; ++m) {
            int row0 = rbase + m * 16;
            #pragma unroll
            for (int r = 0; r < 4; ++r) {
                C[(size_t)(row0 + r) * H_DIM + col] = acc[m][n][r] + bv;
            }
        }
    }
}

// ---------------- launcher ----------------
extern "C" void kernel_launch(void* const* d_in, const int* in_sizes, int n_in,
                              void* d_out, int out_size, void* d_ws, size_t ws_size,
                              hipStream_t stream) {
    const float* a      = (const float*)d_in[0];
    const float* v      = (const float*)d_in[1];
    const float* l      = (const float*)d_in[2];
    const float* qmask  = (const float*)d_in[3];
    // d_in[4] umask: unused by reference
    const float* mu_a   = (const float*)d_in[5];
    const float* mu_v   = (const float*)d_in[6];
    const float* mu_l   = (const float*)d_in[7];
    const float* shifta = (const float*)d_in[8];
    const float* shiftv = (const float*)d_in[9];
    const float* turna  = (const float*)d_in[10];
    const float* turnb  = (const float*)d_in[11];
    const float* W1     = (const float*)d_in[12];
    const float* b1     = (const float*)d_in[13];
    const float* W2     = (const float*)d_in[14];
    // d_in[15] b2: cancels in xr+xi
    float* out = (float*)d_out;

    char* ws = (char*)d_ws;
    unsigned short* Afeat = (unsigned short*)ws;                       // M*K_CAT bf16
    size_t offB  = (size_t)M_DIM * K_CAT * sizeof(unsigned short);     // 57,671,680
    unsigned short* Bt = (unsigned short*)(ws + offB);                 // H*K_CAT bf16
    size_t offBias = offB + (size_t)H_DIM * K_CAT * sizeof(unsigned short);
    float* bias2 = (float*)(ws + offBias);

    prep_w_kernel<<<(H_DIM * K_CAT + 255) / 256, 256, 0, stream>>>(W1, b1, W2, Bt, bias2);
    feat_scan_kernel<<<(B_DIM * D_DIM) / 256, 256, 0, stream>>>(
        a, v, l, qmask, mu_a, mu_v, mu_l, shifta, shiftv, turna, turnb, Afeat);
    dim3 grid(M_DIM / BM, H_DIM / BN);
    gemm_kernel<<<grid, 256, 0, stream>>>(Afeat, Bt, bias2, out);
}